// Round 1
// 403.252 us; speedup vs baseline: 1.2372x; 1.2372x over previous
//
#include <hip/hip_runtime.h>
#include <cmath>
#include <stdint.h>

#define HH 64
#define WD 64
#define CIN 256
#define COUT 256
#define NB 32

typedef _Float16 half8 __attribute__((ext_vector_type(8)));
typedef _Float16 half4 __attribute__((ext_vector_type(4)));
typedef float floatx4 __attribute__((ext_vector_type(4)));

#define SB() __builtin_amdgcn_sched_barrier(0)

__device__ __forceinline__ void glds16(const void* src, void* dst) {
    __builtin_amdgcn_global_load_lds((const __attribute__((address_space(1))) void*)src,
                                     (__attribute__((address_space(3))) void*)dst, 16, 0, 0);
}

// ---------------------------------------------------------------------------
// xprep: NCHW fp32 -> fp16 [n][chunk8][h64][w64][ci32]  (67 MB in ws)
// ---------------------------------------------------------------------------
__global__ __launch_bounds__(256) void xprep_kernel(const float* __restrict__ x,
                                                    _Float16* __restrict__ x16) {
    __shared__ _Float16 lt[32 * 72];
    const int tid = threadIdx.x;
    const int bid = blockIdx.x;           // n*512 + chunk*64 + h
    const int h = bid & 63;
    const int chunk = (bid >> 6) & 7;
    const int n = bid >> 9;
    {
        const int ci = tid >> 3;
        const int w8 = (tid & 7) * 8;
        const float* src = x + (((size_t)(n * 256 + chunk * 32 + ci) * 64 + h) * 64 + w8);
        const float4 a = *(const float4*)src;
        const float4 b = *(const float4*)(src + 4);
        half8 hv;
        hv[0] = (_Float16)a.x; hv[1] = (_Float16)a.y; hv[2] = (_Float16)a.z; hv[3] = (_Float16)a.w;
        hv[4] = (_Float16)b.x; hv[5] = (_Float16)b.y; hv[6] = (_Float16)b.z; hv[7] = (_Float16)b.w;
        *(half8*)&lt[ci * 72 + w8] = hv;
    }
    __syncthreads();
    {
        const int w = tid >> 2;
        const int kc = tid & 3;
        half8 hv;
        #pragma unroll
        for (int j = 0; j < 8; ++j) hv[j] = lt[(kc * 8 + j) * 72 + w];
        *(half8*)&x16[(((size_t)(n * 8 + chunk) * 64 + h) * 64 + w) * 32 + kc * 8] = hv;
    }
}

// ---------------------------------------------------------------------------
// wprep: w [co][ci][3][3] fp32 -> fp16 [chunk8][cb4][tap9][u4][q4][m16][j8]
// block 0 also zero-fills the 4KB zero page used for conv halo rows.
// ---------------------------------------------------------------------------
__global__ __launch_bounds__(256) void wprep_kernel(const float* __restrict__ w,
                                                    _Float16* __restrict__ w16,
                                                    float4* __restrict__ zp) {
    const int idx = blockIdx.x * 256 + threadIdx.x;   // 589,824
    const int j = idx & 7;
    const int m = (idx >> 3) & 15;
    const int q = (idx >> 7) & 3;
    const int u = (idx >> 9) & 3;
    const int rest = idx >> 11;
    const int tap = rest % 9;
    const int rr = rest / 9;
    const int cb = rr & 3;
    const int chunk = rr >> 2;
    const int co = cb * 64 + u * 16 + m;
    const int ci = chunk * 32 + q * 8 + j;
    w16[idx] = (_Float16)w[(co * CIN + ci) * 9 + tap];
    if (blockIdx.x == 0) {
        float4 z; z.x = 0.f; z.y = 0.f; z.z = 0.f; z.w = 0.f;
        zp[threadIdx.x] = z;   // 4 KB of zeros
    }
}

// ---------------------------------------------------------------------------
// gprep1: per-channel circulant generators -> gtab[c][isv][r] fp32
// ---------------------------------------------------------------------------
__global__ __launch_bounds__(256) void gprep1_kernel(const float* __restrict__ alpha,
                                                     float* __restrict__ gtab) {
    const int gid = blockIdx.x * 256 + threadIdx.x;     // 32,768
    const int r   = gid & 63;
    const int isv = (gid >> 6) & 1;
    const int c   = gid >> 7;
    const float t0 = tanhf(alpha[c * 4 + isv * 2 + 0]);
    const float t1 = tanhf(alpha[c * 4 + isv * 2 + 1]);
    const float qq = 0.70710678118654752f;
    const float a0 = qq * (t0 + t1);   // tap -1
    const float a2 = qq * (t1 - t0);   // tap +1
    const float w0 = 0.09817477042468103f; // 2*pi/64
    float ssum = 0.f;
    for (int p = 0; p < 64; ++p) {
        const float th = w0 * (float)p;
        const float re = 1.f + (a0 + a2) * cosf(th);
        const float im = (a0 - a2) * sinf(th);
        const float inv = 1.f / (re * re + im * im);
        const float ph = w0 * (float)((p * r) & 63);
        ssum += (cosf(ph) * re + sinf(ph) * im) * inv;
    }
    gtab[gid] = ssum * (1.0f / 64.0f);
}

// ---------------------------------------------------------------------------
// gprep2: expand to swizzled fp16 circulant matrices
// gm[c][which2][row64][kc8 ^ (row&7)][8],  G[row][col] = g[(row-col)&63]
// ---------------------------------------------------------------------------
__global__ __launch_bounds__(256) void gprep2_kernel(const float* __restrict__ gtab,
                                                     _Float16* __restrict__ gm) {
    const int idx = blockIdx.x * 256 + threadIdx.x;  // 262,144
    const int kc = idx & 7;
    const int row = (idx >> 3) & 63;
    const int which = (idx >> 9) & 1;
    const int c = idx >> 10;
    const float* g = gtab + c * 128 + which * 64;
    half8 hv;
    #pragma unroll
    for (int j = 0; j < 8; ++j)
        hv[j] = (_Float16)g[(row - (kc * 8 + j)) & 63];
    *(half8*)&gm[((size_t)(c * 2 + which) * 64 + row) * 64 + ((kc ^ (row & 7)) * 8)] = hv;
}

// ---------------------------------------------------------------------------
// Conv 3x3 as implicit GEMM, fp16 MFMA 16x16x32.
// 512-thread block (8 waves), tile 64 co x 16 rows x 64 cols.
// Per wave: 2 rows x 64 cols x 64 co, row-reuse across ky (4 af rows feed 6
// (ro,ky) pairs). Double-buffered 2x76KB dynamic LDS; x staged with
// global_load_lds (16B), issued early inside compute so latency hides under
// MFMA. One barrier per chunk. Output written as fp16 into the upper half of
// each plane's fp32 slot in d_out (consumed by solve_mfma).
// ---------------------------------------------------------------------------
__global__ __launch_bounds__(512, 2) void conv_mfma(const _Float16* __restrict__ x16,
                                                    const _Float16* __restrict__ w16,
                                                    const _Float16* __restrict__ zp,
                                                    float* __restrict__ y) {
    extern __shared__ __align__(16) _Float16 xs2[];   // 2 * 18*66*32 halfs = 152,064 B
    const int tid  = threadIdx.x;
    const int lane = tid & 63;
    const int wv   = tid >> 6;          // 0..7
    const int m    = lane & 15;
    const int q    = lane >> 4;

    // XCD-bijective remap: 4 cb-blocks sharing one x-tile land on one XCD.
    const int hw   = blockIdx.x;        // 512 blocks
    const int xcd  = hw & 7;
    const int ii   = hw >> 3;           // 0..63
    const int pair = xcd * 16 + (ii >> 2);   // 0..127 = (ht,n)
    const int cb   = ii & 3;
    const int ht   = pair & 3;
    const int n    = pair >> 2;
    const int h0   = ht * 16;

    // staging decomposition: slot s = it*512 + tid; sr = 2*it + (tid>>8);
    // cx = ((tid>>2)&63)+1; kcs = tid&3.  LDS dest is linear base+lane*16.
    const int s_kcs = tid & 3;
    const int s_cx  = ((tid >> 2) & 63) + 1;
    const int s_gw  = s_cx - 1;
    const int s_kc  = s_kcs ^ (s_cx & 3);
    const int s_cxb = ((wv & 3) << 4) + 1;     // wave-uniform col base
    const int s_sr0 = wv >> 2;                 // wave-uniform row lsb

    // per-lane af column offset (half index) per kx, within (row, cbk=0)
    int aoff[3];
    #pragma unroll
    for (int kx = 0; kx < 3; ++kx)
        aoff[kx] = (m + kx) * 32 + ((q ^ ((m + kx) & 3)) * 8);

    floatx4 acc[2][4][4];
    #pragma unroll
    for (int ro = 0; ro < 2; ++ro)
        #pragma unroll
        for (int cbk = 0; cbk < 4; ++cbk)
            #pragma unroll
            for (int u = 0; u < 4; ++u) acc[ro][cbk][u] = (floatx4)0.f;

    // zero the halo columns (cx = 0 and 65) of both buffers: always zero-pad
    if (tid < 288) {
        const int b   = tid / 144;
        const int r2  = tid - b * 144;
        const int kcs = r2 & 3;
        const int cxe = ((r2 >> 2) & 1) * 65;
        const int row = r2 >> 3;
        *(half8*)&xs2[b * 38016 + (row * 66 + cxe) * 32 + kcs * 8] = (half8)(_Float16)0.f;
    }

    // prologue: stage chunk 0 into buffer 0
    {
        const _Float16* xc0 = x16 + (size_t)(n * 8 + 0) * 131072;
        #pragma unroll
        for (int it = 0; it < 9; ++it) {
            const int sr = 2 * it + s_sr0;
            const int gh = h0 - 1 + sr;
            const _Float16* src = ((unsigned)gh < 64u)
                ? xc0 + ((gh * 64 + s_gw) * 32 + s_kc * 8)
                : zp + (lane << 3);
            _Float16* dst = xs2 + (sr * 66 + s_cxb) * 32;
            glds16(src, dst);
        }
    }
    asm volatile("s_waitcnt vmcnt(0)" ::: "memory");
    __syncthreads();

    for (int c = 0; c < 8; ++c) {
        _Float16* bcur = xs2 + (c & 1) * 38016;
        _Float16* bnxt = xs2 + ((c & 1) ^ 1) * 38016;
        const _Float16* wchunk = w16 + (size_t)(c * 4 + cb) * 18432;
        const _Float16* xcn = x16 + (size_t)(n * 8 + ((c + 1) & 7)) * 131072;
        const bool pf = (c < 7);

        #pragma unroll
        for (int kx = 0; kx < 3; ++kx) {
            half8 bf[3][4];
            #pragma unroll
            for (int ky = 0; ky < 3; ++ky)
                #pragma unroll
                for (int u = 0; u < 4; ++u)
                    bf[ky][u] = *(const half8*)&wchunk[(ky * 3 + kx) * 2048 + u * 512 + lane * 8];

            // early-issued staging of next chunk (5 after kx0 loads, 4 after kx1)
            if (kx == 0 && pf) {
                SB();
                #pragma unroll
                for (int it = 0; it < 5; ++it) {
                    const int sr = 2 * it + s_sr0;
                    const int gh = h0 - 1 + sr;
                    const _Float16* src = ((unsigned)gh < 64u)
                        ? xcn + ((gh * 64 + s_gw) * 32 + s_kc * 8)
                        : zp + (lane << 3);
                    glds16(src, bnxt + (sr * 66 + s_cxb) * 32);
                }
                SB();
            }
            if (kx == 1 && pf) {
                SB();
                #pragma unroll
                for (int it = 5; it < 9; ++it) {
                    const int sr = 2 * it + s_sr0;
                    const int gh = h0 - 1 + sr;
                    const _Float16* src = ((unsigned)gh < 64u)
                        ? xcn + ((gh * 64 + s_gw) * 32 + s_kc * 8)
                        : zp + (lane << 3);
                    glds16(src, bnxt + (sr * 66 + s_cxb) * 32);
                }
                SB();
            }

            #pragma unroll
            for (int cbk = 0; cbk < 4; ++cbk) {
                half8 af[4];
                #pragma unroll
                for (int rr = 0; rr < 4; ++rr)
                    af[rr] = *(const half8*)&bcur[(wv * 2 + rr) * 2112 + cbk * 512 + aoff[kx]];
                #pragma unroll
                for (int ro = 0; ro < 2; ++ro)
                    #pragma unroll
                    for (int ky = 0; ky < 3; ++ky)
                        #pragma unroll
                        for (int u = 0; u < 4; ++u)
                            acc[ro][cbk][u] = __builtin_amdgcn_mfma_f32_16x16x32_f16(
                                bf[ky][u], af[ro + ky], acc[ro][cbk][u], 0, 0, 0);
            }
        }
        asm volatile("s_waitcnt vmcnt(0)" ::: "memory");
        __syncthreads();
    }

    // epilogue: write fp16 y into upper half of each plane's 16KB slot in d_out
    _Float16* y16o = (_Float16*)y;
    #pragma unroll
    for (int u = 0; u < 4; ++u) {
        #pragma unroll
        for (int r = 0; r < 4; ++r) {
            const int co = cb * 64 + u * 16 + q * 4 + r;
            _Float16* yp = y16o + (size_t)(n * COUT + co) * 8192 + 4096;
            #pragma unroll
            for (int ro = 0; ro < 2; ++ro)
                #pragma unroll
                for (int cbk = 0; cbk < 4; ++cbk)
                    yp[(h0 + wv * 2 + ro) * 64 + cbk * 16 + m] = (_Float16)acc[ro][cbk][u][r];
        }
    }
}

// ---------------------------------------------------------------------------
// Solve: per plane, Out = Gu * (Y * Gv^T) via two fp16 MFMA GEMMs.
// Y read as fp16 from the interleaved region conv wrote (global_load_lds with
// pre-swizzled source); final fp32 written over the plane slot.
// ---------------------------------------------------------------------------
__global__ __launch_bounds__(256, 4) void solve_mfma(const _Float16* __restrict__ gm,
                                                     float* __restrict__ y) {
    __shared__ __align__(16) _Float16 Ys[64 * 64];
    __shared__ __align__(16) _Float16 Tt[64 * 64];
    __shared__ __align__(16) _Float16 Gsh[2 * 64 * 64];
    const int tid  = threadIdx.x;
    const int lane = tid & 63;
    const int wv   = tid >> 6;
    const int m    = lane & 15;
    const int q    = lane >> 4;
    const int plane = blockIdx.x;       // n*256 + c
    const int c = plane & 255;
    float* yp = y + (size_t)plane * 4096;
    const _Float16* ysrc = (const _Float16*)y + (size_t)plane * 8192 + 4096;

    // stage Y (fp16, swizzled source -> linear LDS = swizzled layout)
    {
        #pragma unroll
        for (int it = 0; it < 2; ++it) {
            const int s   = it * 256 + tid;
            const int r   = s >> 3;
            const int kcs = s & 7;
            const int kc  = kcs ^ (r & 7);
            const _Float16* src = ysrc + r * 64 + kc * 8;
            _Float16* dst = Ys + (it * 256 + wv * 64) * 8;
            glds16(src, dst);
        }
        // stage G (already swizzled in ws) — linear copy
        const _Float16* gsrc = gm + (size_t)c * 8192;
        #pragma unroll
        for (int it = 0; it < 4; ++it) {
            const _Float16* src = gsrc + (size_t)(it * 256 + tid) * 8;
            _Float16* dst = Gsh + (it * 256 + wv * 64) * 8;
            glds16(src, dst);
        }
    }
    asm volatile("s_waitcnt vmcnt(0)" ::: "memory");
    __syncthreads();

    // GEMM1: T = Y * Gv^T ; lane holds T[16wv+q*4+r][u*16+m] -> write Tt[s][r]
    {
        floatx4 acc1[4];
        #pragma unroll
        for (int u = 0; u < 4; ++u) acc1[u] = (floatx4)0.f;
        #pragma unroll
        for (int ks = 0; ks < 2; ++ks) {
            const int swz = ((ks * 4 + q) ^ (m & 7)) * 8;
            const half8 yf = *(const half8*)&Ys[(16 * wv + m) * 64 + swz];
            #pragma unroll
            for (int u = 0; u < 4; ++u) {
                const half8 gvf = *(const half8*)&Gsh[4096 + (u * 16 + m) * 64 + swz];
                acc1[u] = __builtin_amdgcn_mfma_f32_16x16x32_f16(yf, gvf, acc1[u], 0, 0, 0);
            }
        }
        #pragma unroll
        for (int u = 0; u < 4; ++u) {
            half4 hv;
            #pragma unroll
            for (int r = 0; r < 4; ++r) hv[r] = (_Float16)acc1[u][r];
            const int s = u * 16 + m;
            const int kc = 2 * wv + (q >> 1);
            *(half4*)&Tt[s * 64 + ((kc ^ (s & 7)) * 8) + (q & 1) * 4] = hv;
        }
    }
    __syncthreads();

    // GEMM2: Out = Gu * T ; store fp32 in-place
    {
        floatx4 acc2[4];
        #pragma unroll
        for (int u = 0; u < 4; ++u) acc2[u] = (floatx4)0.f;
        #pragma unroll
        for (int ks = 0; ks < 2; ++ks) {
            const int swz = ((ks * 4 + q) ^ (m & 7)) * 8;
            const half8 guf = *(const half8*)&Gsh[(16 * wv + m) * 64 + swz];
            #pragma unroll
            for (int u = 0; u < 4; ++u) {
                const half8 ttf = *(const half8*)&Tt[(u * 16 + m) * 64 + swz];
                acc2[u] = __builtin_amdgcn_mfma_f32_16x16x32_f16(guf, ttf, acc2[u], 0, 0, 0);
            }
        }
        #pragma unroll
        for (int u = 0; u < 4; ++u)
            #pragma unroll
            for (int r = 0; r < 4; ++r)
                yp[(16 * wv + q * 4 + r) * 64 + u * 16 + m] = acc2[u][r];
    }
}

extern "C" void kernel_launch(void* const* d_in, const int* in_sizes, int n_in,
                              void* d_out, int out_size, void* d_ws, size_t ws_size,
                              hipStream_t stream) {
    const float* x     = (const float*)d_in[0];
    const float* w     = (const float*)d_in[1];
    const float* alpha = (const float*)d_in[2];
    float* y = (float*)d_out;

    // workspace layout (bytes)
    _Float16* x16 = (_Float16*)d_ws;                               // 67,108,864 B
    _Float16* w16 = (_Float16*)((char*)d_ws + 67108864);           //  1,179,648 B
    _Float16* gm  = (_Float16*)((char*)d_ws + 68288512);           //  4,194,304 B
    float*    gtab = (float*)((char*)d_ws + 72482816);             //    131,072 B
    float4*   zp   = (float4*)((char*)d_ws + 72613888);            //      4,096 B

    static bool inited = false;
    if (!inited) {
        hipFuncSetAttribute((const void*)conv_mfma,
                            hipFuncAttributeMaxDynamicSharedMemorySize, 152064);
        inited = true;
    }

    xprep_kernel <<<dim3(32 * 8 * 64), 256, 0, stream>>>(x, x16);
    wprep_kernel <<<dim3(2304),        256, 0, stream>>>(w, w16, zp);
    gprep1_kernel<<<dim3(128),         256, 0, stream>>>(alpha, gtab);
    gprep2_kernel<<<dim3(1024),        256, 0, stream>>>(gtab, gm);
    conv_mfma    <<<dim3(512),         512, 152064, stream>>>(x16, w16, (const _Float16*)zp, y);
    solve_mfma   <<<dim3(NB * COUT),   256, 0, stream>>>(gm, y);
}

// Round 2
// 390.394 us; speedup vs baseline: 1.2779x; 1.0329x over previous
//
#include <hip/hip_runtime.h>
#include <cmath>
#include <stdint.h>

#define HH 64
#define WD 64
#define CIN 256
#define COUT 256
#define NB 32

typedef _Float16 half8 __attribute__((ext_vector_type(8)));
typedef _Float16 half4 __attribute__((ext_vector_type(4)));
typedef float floatx4 __attribute__((ext_vector_type(4)));

#define SB() __builtin_amdgcn_sched_barrier(0)

__device__ __forceinline__ void glds16(const void* src, void* dst) {
    __builtin_amdgcn_global_load_lds((const __attribute__((address_space(1))) void*)src,
                                     (__attribute__((address_space(3))) void*)dst, 16, 0, 0);
}

// ---------------------------------------------------------------------------
// xprep: NCHW fp32 -> fp16 [n][chunk8][h64][w64][ci32]  (67 MB in ws)
// ---------------------------------------------------------------------------
__global__ __launch_bounds__(256) void xprep_kernel(const float* __restrict__ x,
                                                    _Float16* __restrict__ x16) {
    __shared__ _Float16 lt[32 * 72];
    const int tid = threadIdx.x;
    const int bid = blockIdx.x;           // n*512 + chunk*64 + h
    const int h = bid & 63;
    const int chunk = (bid >> 6) & 7;
    const int n = bid >> 9;
    {
        const int ci = tid >> 3;
        const int w8 = (tid & 7) * 8;
        const float* src = x + (((size_t)(n * 256 + chunk * 32 + ci) * 64 + h) * 64 + w8);
        const float4 a = *(const float4*)src;
        const float4 b = *(const float4*)(src + 4);
        half8 hv;
        hv[0] = (_Float16)a.x; hv[1] = (_Float16)a.y; hv[2] = (_Float16)a.z; hv[3] = (_Float16)a.w;
        hv[4] = (_Float16)b.x; hv[5] = (_Float16)b.y; hv[6] = (_Float16)b.z; hv[7] = (_Float16)b.w;
        *(half8*)&lt[ci * 72 + w8] = hv;
    }
    __syncthreads();
    {
        const int w = tid >> 2;
        const int kc = tid & 3;
        half8 hv;
        #pragma unroll
        for (int j = 0; j < 8; ++j) hv[j] = lt[(kc * 8 + j) * 72 + w];
        *(half8*)&x16[(((size_t)(n * 8 + chunk) * 64 + h) * 64 + w) * 32 + kc * 8] = hv;
    }
}

// ---------------------------------------------------------------------------
// wprep: w [co][ci][3][3] fp32 -> fp16 [chunk8][cb4][tap9][u4][q4][m16][j8]
// block 0 also zero-fills the 4KB zero page used for conv halo rows/cols.
// ---------------------------------------------------------------------------
__global__ __launch_bounds__(256) void wprep_kernel(const float* __restrict__ w,
                                                    _Float16* __restrict__ w16,
                                                    float4* __restrict__ zp) {
    const int idx = blockIdx.x * 256 + threadIdx.x;   // 589,824
    const int j = idx & 7;
    const int m = (idx >> 3) & 15;
    const int q = (idx >> 7) & 3;
    const int u = (idx >> 9) & 3;
    const int rest = idx >> 11;
    const int tap = rest % 9;
    const int rr = rest / 9;
    const int cb = rr & 3;
    const int chunk = rr >> 2;
    const int co = cb * 64 + u * 16 + m;
    const int ci = chunk * 32 + q * 8 + j;
    w16[idx] = (_Float16)w[(co * CIN + ci) * 9 + tap];
    if (blockIdx.x == 0) {
        float4 z; z.x = 0.f; z.y = 0.f; z.z = 0.f; z.w = 0.f;
        zp[threadIdx.x] = z;   // 4 KB of zeros
    }
}

// ---------------------------------------------------------------------------
// gprep1: per-channel circulant generators -> gtab[c][isv][r] fp32
// all phases are exact multiples of 2*pi/64 -> use v_sin/v_cos on revolutions
// ---------------------------------------------------------------------------
__global__ __launch_bounds__(256) void gprep1_kernel(const float* __restrict__ alpha,
                                                     float* __restrict__ gtab) {
    const int gid = blockIdx.x * 256 + threadIdx.x;     // 32,768
    const int r   = gid & 63;
    const int isv = (gid >> 6) & 1;
    const int c   = gid >> 7;
    const float t0 = tanhf(alpha[c * 4 + isv * 2 + 0]);
    const float t1 = tanhf(alpha[c * 4 + isv * 2 + 1]);
    const float qq = 0.70710678118654752f;
    const float a0 = qq * (t0 + t1);   // tap -1
    const float a2 = qq * (t1 - t0);   // tap +1
    const float rev = 0.015625f;       // 1/64 revolution
    float ssum = 0.f;
    for (int p = 0; p < 64; ++p) {
        const float pr = (float)p * rev;
        const float re = 1.f + (a0 + a2) * __builtin_amdgcn_cosf(pr);
        const float im = (a0 - a2) * __builtin_amdgcn_sinf(pr);
        const float inv = 1.f / (re * re + im * im);
        const float ph = (float)((p * r) & 63) * rev;
        ssum += (__builtin_amdgcn_cosf(ph) * re + __builtin_amdgcn_sinf(ph) * im) * inv;
    }
    gtab[gid] = ssum * (1.0f / 64.0f);
}

// ---------------------------------------------------------------------------
// gprep2: expand to swizzled fp16 circulant matrices
// gm[c][which2][row64][kc8 ^ (row&7)][8],  G[row][col] = g[(row-col)&63]
// ---------------------------------------------------------------------------
__global__ __launch_bounds__(256) void gprep2_kernel(const float* __restrict__ gtab,
                                                     _Float16* __restrict__ gm) {
    const int idx = blockIdx.x * 256 + threadIdx.x;  // 262,144
    const int kc = idx & 7;
    const int row = (idx >> 3) & 63;
    const int which = (idx >> 9) & 1;
    const int c = idx >> 10;
    const float* g = gtab + c * 128 + which * 64;
    half8 hv;
    #pragma unroll
    for (int j = 0; j < 8; ++j)
        hv[j] = (_Float16)g[(row - (kc * 8 + j)) & 63];
    *(half8*)&gm[((size_t)(c * 2 + which) * 64 + row) * 64 + ((kc ^ (row & 7)) * 8)] = hv;
}

// ---------------------------------------------------------------------------
// Conv 3x3 as implicit GEMM, fp16 MFMA 16x16x32.
// 256-thread block (4 waves), tile 64co x 16rows x 32cols.
// Wave: 64co x 4rows x 32px (acc 128 AGPR); ky-row-reuse: 6 staged rows feed
// 12 (ro,ky) pairs. LDS dbuf 2x39,168B -> 2 blocks/CU (barrier-decoupled).
// x staged via global_load_lds (16B slots, pre-swizzled source), issued early
// inside compute; one barrier per chunk; setprio around MFMA clusters.
// Output fp16 into upper half of each plane's fp32 slot in d_out.
// ---------------------------------------------------------------------------
__global__ __launch_bounds__(256, 2) void conv_mfma(const _Float16* __restrict__ x16,
                                                    const _Float16* __restrict__ w16,
                                                    const _Float16* __restrict__ zp,
                                                    float* __restrict__ y) {
    extern __shared__ __align__(16) _Float16 xs2[];   // 2 * 19,584 halfs = 78,336 B
    const int tid  = threadIdx.x;
    const int lane = tid & 63;
    const int wv   = tid >> 6;          // 0..3
    const int m    = lane & 15;
    const int q    = lane >> 4;

    // XCD-bijective remap: the 8 (cb,wt) blocks of one (n,ht) land on one XCD.
    const int bid  = blockIdx.x;        // 1024
    const int xcd  = bid & 7;
    const int idx  = bid >> 3;          // 0..127
    const int sub  = idx & 7;
    const int cb   = sub >> 1;          // 0..3
    const int wt   = sub & 1;           // 0..1
    const int pair = xcd * 16 + (idx >> 3);   // 0..127 = (ht,n)
    const int ht   = pair & 3;
    const int n    = pair >> 2;
    const int h0   = ht * 16;
    const int w0   = wt * 32;

    // staging: 2448 slots of 16B; slot = row*136 + col*4 + octp (rows 18, cols 34)
    // stored data = x[h0-1+row][w0-1+col][oct = octp ^ (col&3)]  (pre-swizzled src)
    int soff[10];
    #pragma unroll
    for (int it = 0; it < 10; ++it) {
        const int slot = it * 256 + tid;
        const int row  = (slot * 7711) >> 20;        // floor(slot/136), slot<2448
        const int rem  = slot - row * 136;
        const int col  = rem >> 2;
        const int oct  = (rem & 3) ^ (col & 3);
        const int gh   = h0 - 1 + row;
        const int gw   = w0 - 1 + col;
        soff[it] = ((unsigned)gh < 64u && (unsigned)gw < 64u)
                 ? ((gh * 64 + gw) * 32 + oct * 8) : -1;
    }

    // per-lane af column offset (halfs) per kx within (row, cbk=0)
    int aoff[3];
    #pragma unroll
    for (int kx = 0; kx < 3; ++kx)
        aoff[kx] = (m + kx) * 32 + ((q ^ ((m + kx) & 3)) * 8);

    floatx4 acc[4][2][4];
    #pragma unroll
    for (int ro = 0; ro < 4; ++ro)
        #pragma unroll
        for (int cbk = 0; cbk < 2; ++cbk)
            #pragma unroll
            for (int u = 0; u < 4; ++u) acc[ro][cbk][u] = (floatx4)0.f;

    // prologue: stage chunk 0 into buffer 0
    {
        const _Float16* xc0 = x16 + (size_t)n * 1048576;
        #pragma unroll
        for (int it = 0; it < 10; ++it) {
            if (it * 256 + tid < 2448) {
                const _Float16* src = (soff[it] >= 0) ? xc0 + soff[it] : zp + (lane << 3);
                glds16(src, xs2 + (size_t)(it * 256 + wv * 64) * 8);
            }
        }
    }
    asm volatile("s_waitcnt vmcnt(0)" ::: "memory");
    __syncthreads();

    for (int c = 0; c < 8; ++c) {
        _Float16* bcur = xs2 + (c & 1) * 19584;
        _Float16* bnxt = xs2 + ((c & 1) ^ 1) * 19584;
        const _Float16* wchunk = w16 + (size_t)(c * 4 + cb) * 18432;
        const _Float16* xcn = x16 + (size_t)(n * 8 + c + 1) * 131072;
        const bool pf = (c < 7);

        #pragma unroll
        for (int kx = 0; kx < 3; ++kx) {
            half8 bf[3][4];
            #pragma unroll
            for (int ky = 0; ky < 3; ++ky)
                #pragma unroll
                for (int u = 0; u < 4; ++u)
                    bf[ky][u] = *(const half8*)&wchunk[(ky * 3 + kx) * 2048 + u * 512 + lane * 8];

            // early-issued staging of next chunk (5 iters after kx0, 5 after kx1)
            if (kx == 0 && pf) {
                SB();
                #pragma unroll
                for (int it = 0; it < 5; ++it) {
                    const _Float16* src = (soff[it] >= 0) ? xcn + soff[it] : zp + (lane << 3);
                    glds16(src, bnxt + (size_t)(it * 256 + wv * 64) * 8);
                }
                SB();
            }
            if (kx == 1 && pf) {
                SB();
                #pragma unroll
                for (int it = 5; it < 10; ++it) {
                    if (it * 256 + tid < 2448) {
                        const _Float16* src = (soff[it] >= 0) ? xcn + soff[it] : zp + (lane << 3);
                        glds16(src, bnxt + (size_t)(it * 256 + wv * 64) * 8);
                    }
                }
                SB();
            }

            #pragma unroll
            for (int cbk = 0; cbk < 2; ++cbk) {
                half8 af[6];
                #pragma unroll
                for (int rr = 0; rr < 6; ++rr)
                    af[rr] = *(const half8*)&bcur[(wv * 4 + rr) * 1088 + cbk * 512 + aoff[kx]];
                __builtin_amdgcn_s_setprio(1);
                #pragma unroll
                for (int ro = 0; ro < 4; ++ro)
                    #pragma unroll
                    for (int ky = 0; ky < 3; ++ky)
                        #pragma unroll
                        for (int u = 0; u < 4; ++u)
                            acc[ro][cbk][u] = __builtin_amdgcn_mfma_f32_16x16x32_f16(
                                bf[ky][u], af[ro + ky], acc[ro][cbk][u], 0, 0, 0);
                __builtin_amdgcn_s_setprio(0);
            }
        }
        asm volatile("s_waitcnt vmcnt(0)" ::: "memory");
        __syncthreads();
    }

    // epilogue: fp16 y into upper half of each plane's 16KB slot in d_out
    _Float16* y16o = (_Float16*)y;
    #pragma unroll
    for (int u = 0; u < 4; ++u) {
        #pragma unroll
        for (int r = 0; r < 4; ++r) {
            const int co = cb * 64 + u * 16 + q * 4 + r;
            _Float16* yp = y16o + (size_t)(n * COUT + co) * 8192 + 4096;
            #pragma unroll
            for (int ro = 0; ro < 4; ++ro)
                #pragma unroll
                for (int cbk = 0; cbk < 2; ++cbk)
                    yp[(h0 + wv * 4 + ro) * 64 + w0 + cbk * 16 + m] = (_Float16)acc[ro][cbk][u][r];
        }
    }
}

// ---------------------------------------------------------------------------
// Solve: Out = Gu * (Y * Gv^T), two fp16 MFMA GEMMs per plane.
// Block = (c, 4 consecutive n): G staged once, Y double-buffered via
// global_load_lds issued before GEMM1 of the previous plane. 40KB LDS,
// 4 blocks/CU. Final fp32 written over the plane slot.
// ---------------------------------------------------------------------------
__global__ __launch_bounds__(256, 4) void solve_mfma(const _Float16* __restrict__ gm,
                                                     float* __restrict__ y) {
    __shared__ __align__(16) _Float16 Ysd[2][64 * 64];
    __shared__ __align__(16) _Float16 Tt[64 * 64];
    __shared__ __align__(16) _Float16 Gsh[2 * 64 * 64];
    const int tid  = threadIdx.x;
    const int lane = tid & 63;
    const int wv   = tid >> 6;
    const int m    = lane & 15;
    const int q    = lane >> 4;
    const int bid  = blockIdx.x;        // 2048
    const int nq   = bid & 7;
    const int c    = bid >> 3;

    // stage G (already swizzled in ws)
    {
        const _Float16* gsrc = gm + (size_t)c * 8192;
        #pragma unroll
        for (int it = 0; it < 4; ++it)
            glds16(gsrc + (size_t)(it * 256 + tid) * 8, Gsh + (size_t)(it * 256 + wv * 64) * 8);
    }
    // stage Y plane 0 (fp16, pre-swizzled source -> linear LDS)
    {
        const _Float16* ysrc = (const _Float16*)y + ((size_t)(nq * 4 + 0) * 256 + c) * 8192 + 4096;
        #pragma unroll
        for (int it = 0; it < 2; ++it) {
            const int s  = it * 256 + tid;
            const int r  = s >> 3;
            const int kc = (s & 7) ^ (r & 7);
            glds16(ysrc + r * 64 + kc * 8, Ysd[0] + (size_t)(it * 256 + wv * 64) * 8);
        }
    }
    asm volatile("s_waitcnt vmcnt(0)" ::: "memory");
    __syncthreads();

    #pragma unroll
    for (int i = 0; i < 4; ++i) {
        const _Float16* Ys = Ysd[i & 1];
        if (i < 3) {   // prefetch Y of plane i+1 into the other buffer
            const _Float16* ysrc = (const _Float16*)y + ((size_t)(nq * 4 + i + 1) * 256 + c) * 8192 + 4096;
            #pragma unroll
            for (int it = 0; it < 2; ++it) {
                const int s  = it * 256 + tid;
                const int r  = s >> 3;
                const int kc = (s & 7) ^ (r & 7);
                glds16(ysrc + r * 64 + kc * 8, Ysd[(i & 1) ^ 1] + (size_t)(it * 256 + wv * 64) * 8);
            }
        }

        // GEMM1: T = Y * Gv^T ; lane holds T[16wv+q*4+r][u*16+m] -> write Tt[s][r]
        {
            floatx4 acc1[4];
            #pragma unroll
            for (int u = 0; u < 4; ++u) acc1[u] = (floatx4)0.f;
            #pragma unroll
            for (int ks = 0; ks < 2; ++ks) {
                const int swz = ((ks * 4 + q) ^ (m & 7)) * 8;
                const half8 yf = *(const half8*)&Ys[(16 * wv + m) * 64 + swz];
                #pragma unroll
                for (int u = 0; u < 4; ++u) {
                    const half8 gvf = *(const half8*)&Gsh[4096 + (u * 16 + m) * 64 + swz];
                    acc1[u] = __builtin_amdgcn_mfma_f32_16x16x32_f16(yf, gvf, acc1[u], 0, 0, 0);
                }
            }
            #pragma unroll
            for (int u = 0; u < 4; ++u) {
                half4 hv;
                #pragma unroll
                for (int r = 0; r < 4; ++r) hv[r] = (_Float16)acc1[u][r];
                const int s = u * 16 + m;
                const int kc = 2 * wv + (q >> 1);
                *(half4*)&Tt[s * 64 + ((kc ^ (s & 7)) * 8) + (q & 1) * 4] = hv;
            }
        }
        __syncthreads();

        // GEMM2: Out = Gu * T ; store fp32 in-place
        {
            float* yp = y + ((size_t)(nq * 4 + i) * 256 + c) * 4096;
            floatx4 acc2[4];
            #pragma unroll
            for (int u = 0; u < 4; ++u) acc2[u] = (floatx4)0.f;
            #pragma unroll
            for (int ks = 0; ks < 2; ++ks) {
                const int swz = ((ks * 4 + q) ^ (m & 7)) * 8;
                const half8 guf = *(const half8*)&Gsh[(16 * wv + m) * 64 + swz];
                #pragma unroll
                for (int u = 0; u < 4; ++u) {
                    const half8 ttf = *(const half8*)&Tt[(u * 16 + m) * 64 + swz];
                    acc2[u] = __builtin_amdgcn_mfma_f32_16x16x32_f16(guf, ttf, acc2[u], 0, 0, 0);
                }
            }
            #pragma unroll
            for (int u = 0; u < 4; ++u)
                #pragma unroll
                for (int r = 0; r < 4; ++r)
                    yp[(16 * wv + q * 4 + r) * 64 + u * 16 + m] = acc2[u][r];
        }
        if (i < 3) {
            asm volatile("s_waitcnt vmcnt(0)" ::: "memory");
            __syncthreads();
        }
    }
}

extern "C" void kernel_launch(void* const* d_in, const int* in_sizes, int n_in,
                              void* d_out, int out_size, void* d_ws, size_t ws_size,
                              hipStream_t stream) {
    const float* x     = (const float*)d_in[0];
    const float* w     = (const float*)d_in[1];
    const float* alpha = (const float*)d_in[2];
    float* y = (float*)d_out;

    // workspace layout (bytes)
    _Float16* x16 = (_Float16*)d_ws;                               // 67,108,864 B
    _Float16* w16 = (_Float16*)((char*)d_ws + 67108864);           //  1,179,648 B
    _Float16* gm  = (_Float16*)((char*)d_ws + 68288512);           //  4,194,304 B
    float*    gtab = (float*)((char*)d_ws + 72482816);             //    131,072 B
    float4*   zp   = (float4*)((char*)d_ws + 72613888);            //      4,096 B

    static bool inited = false;
    if (!inited) {
        hipFuncSetAttribute((const void*)conv_mfma,
                            hipFuncAttributeMaxDynamicSharedMemorySize, 78336);
        inited = true;
    }

    xprep_kernel <<<dim3(32 * 8 * 64), 256, 0, stream>>>(x, x16);
    wprep_kernel <<<dim3(2304),        256, 0, stream>>>(w, w16, zp);
    gprep1_kernel<<<dim3(128),         256, 0, stream>>>(alpha, gtab);
    gprep2_kernel<<<dim3(1024),        256, 0, stream>>>(gtab, gm);
    conv_mfma    <<<dim3(1024),        256, 78336, stream>>>(x16, w16, (const _Float16*)zp, y);
    solve_mfma   <<<dim3(2048),        256, 0, stream>>>(gm, y);
}